// Round 1
// baseline (37.407 us; speedup 1.0000x reference)
//
#include <hip/hip_runtime.h>

namespace {

constexpr int H = 256;
constexpr int Wd = 256;
constexpr int TILE = 16;
constexpr float EPS9 = 1e-7f / 9.0f;
constexpr float NINTH = 1.0f / 9.0f;

// One block = one 16x16 pixel tile of one batch image pair.
// LDS: image tile with +2 halo (20x20, 6 channels = 2 images x 3ch),
//      per-window-center stats (18x18 centers = tile +1 halo):
//      mu(3) + inv-cov upper-tri(6), per image, 12-float record (48B aligned),
//      plus a validity scale (1/9 for interior centers, 0 otherwise).
__global__ __launch_bounds__(256)
void matting_loss_kernel(const float* __restrict__ content,
                         const float* __restrict__ stylized,
                         float* __restrict__ out,
                         float inv_denom)
{
    const int b  = blockIdx.z;
    const int x0 = blockIdx.x * TILE;
    const int y0 = blockIdx.y * TILE;
    const int tid = threadIdx.x;
    const int tx = tid & (TILE - 1);
    const int ty = tid >> 4;

    __shared__ float s_img[20][20][8];        // [y][x][img*3+ch], pad to 8 for b128 reads
    __shared__ float s_stat[2][18][18][12];   // [img][cy][cx][mu0..2, a00,a01,a02,a11,a12,a22, pad]
    __shared__ float s_scale[18][18];         // 1/9 if center valid else 0
    __shared__ float s_red[4];

    const size_t bofs = (size_t)b * 3 * H * Wd;
    const float* imgs[2] = { content + bofs, stylized + bofs };

    // ---- Phase 1: load image tile + halo (clamped; clamped pixels only feed
    //      invalid centers whose scale is 0, so values just need to be finite) ----
    for (int p = tid; p < 400; p += 256) {
        const int py = p / 20, px = p - py * 20;
        const int gy = min(max(y0 - 2 + py, 0), H - 1);
        const int gx = min(max(x0 - 2 + px, 0), Wd - 1);
        const int gi = gy * Wd + gx;
        #pragma unroll
        for (int m = 0; m < 2; ++m) {
            s_img[py][px][m * 3 + 0] = imgs[m][0 * H * Wd + gi];
            s_img[py][px][m * 3 + 1] = imgs[m][1 * H * Wd + gi];
            s_img[py][px][m * 3 + 2] = imgs[m][2 * H * Wd + gi];
        }
    }
    __syncthreads();

    // ---- Phase 2: per-center stats (mean + inverse covariance) ----
    for (int p = tid; p < 324; p += 256) {
        const int cy = p / 18, cx = p - cy * 18;
        const int gy = y0 - 1 + cy, gx = x0 - 1 + cx;
        const bool valid = (gy >= 1) && (gy <= H - 2) && (gx >= 1) && (gx <= Wd - 2);
        s_scale[cy][cx] = valid ? NINTH : 0.0f;
        #pragma unroll
        for (int m = 0; m < 2; ++m) {
            float s0=0.f,s1=0.f,s2=0.f,q00=0.f,q01=0.f,q02=0.f,q11=0.f,q12=0.f,q22=0.f;
            #pragma unroll
            for (int wy = 0; wy < 3; ++wy)
                #pragma unroll
                for (int wx = 0; wx < 3; ++wx) {
                    const float v0 = s_img[cy + wy][cx + wx][m * 3 + 0];
                    const float v1 = s_img[cy + wy][cx + wx][m * 3 + 1];
                    const float v2 = s_img[cy + wy][cx + wx][m * 3 + 2];
                    s0 += v0; s1 += v1; s2 += v2;
                    q00 += v0 * v0; q01 += v0 * v1; q02 += v0 * v2;
                    q11 += v1 * v1; q12 += v1 * v2; q22 += v2 * v2;
                }
            const float mu0 = s0 * NINTH, mu1 = s1 * NINTH, mu2 = s2 * NINTH;
            const float c00 = q00 * NINTH - mu0 * mu0 + EPS9;
            const float c01 = q01 * NINTH - mu0 * mu1;
            const float c02 = q02 * NINTH - mu0 * mu2;
            const float c11 = q11 * NINTH - mu1 * mu1 + EPS9;
            const float c12 = q12 * NINTH - mu1 * mu2;
            const float c22 = q22 * NINTH - mu2 * mu2 + EPS9;
            const float m00 = c11 * c22 - c12 * c12;
            const float m01 = c02 * c12 - c01 * c22;
            const float m02 = c01 * c12 - c02 * c11;
            const float det = c00 * m00 + c01 * m01 + c02 * m02;
            // invalid centers: never divide (det may be ~0 on clamped data);
            // A = 0 keeps all downstream math finite, scale=0 kills contribution.
            const float invdet = valid ? (1.0f / det) : 0.0f;
            float* st = s_stat[m][cy][cx];
            st[0] = mu0; st[1] = mu1; st[2] = mu2;
            st[3] = m00 * invdet;
            st[4] = m01 * invdet;
            st[5] = m02 * invdet;
            st[6] = (c00 * c22 - c02 * c02) * invdet;
            st[7] = (c01 * c02 - c00 * c12) * invdet;
            st[8] = (c00 * c11 - c01 * c01) * invdet;
        }
    }
    __syncthreads();

    // ---- Phase 3: per-pixel band accumulation ----
    const int ciy = ty + 1, cix = tx + 1;   // this pixel in center-grid coords
    const int iy  = ty + 2, ix  = tx + 2;   // this pixel in image-tile coords

    float I0[6];
    #pragma unroll
    for (int q = 0; q < 6; ++q) I0[q] = s_img[iy][ix][q];

    float w0[25], w1[25];
    #pragma unroll
    for (int q = 0; q < 25; ++q) { w0[q] = 0.f; w1[q] = 0.f; }

    #pragma unroll
    for (int ey = -1; ey <= 1; ++ey)
    #pragma unroll
    for (int ex = -1; ex <= 1; ++ex) {
        const int cy = ciy + ey, cx = cix + ex;
        const float s = s_scale[cy][cx];
        const float* sa = s_stat[0][cy][cx];
        const float* sb = s_stat[1][cy][cx];
        const float amu0 = sa[0], amu1 = sa[1], amu2 = sa[2];
        const float a00 = sa[3], a01 = sa[4], a02 = sa[5];
        const float a11 = sa[6], a12 = sa[7], a22 = sa[8];
        const float bmu0 = sb[0], bmu1 = sb[1], bmu2 = sb[2];
        const float b00 = sb[3], b01 = sb[4], b02 = sb[5];
        const float b11 = sb[6], b12 = sb[7], b22 = sb[8];
        // u_i = I_i - mu ; hoist t = A * u_i (quad = t . (I_j - mu))
        const float ua0 = I0[0] - amu0, ua1 = I0[1] - amu1, ua2 = I0[2] - amu2;
        const float ub0 = I0[3] - bmu0, ub1 = I0[4] - bmu1, ub2 = I0[5] - bmu2;
        const float ta0 = a00 * ua0 + a01 * ua1 + a02 * ua2;
        const float ta1 = a01 * ua0 + a11 * ua1 + a12 * ua2;
        const float ta2 = a02 * ua0 + a12 * ua1 + a22 * ua2;
        const float tb0 = b00 * ub0 + b01 * ub1 + b02 * ub2;
        const float tb1 = b01 * ub0 + b11 * ub1 + b12 * ub2;
        const float tb2 = b02 * ub0 + b12 * ub1 + b22 * ub2;
        #pragma unroll
        for (int fy = -1; fy <= 1; ++fy)
        #pragma unroll
        for (int fx = -1; fx <= 1; ++fx) {
            const int band = (ey + fy + 2) * 5 + (ex + fx + 2);   // compile-time const
            const int jy = iy + ey + fy, jx = ix + ex + fx;
            const float* J = s_img[jy][jx];
            const float quad0 = ta0 * (J[0] - amu0) + ta1 * (J[1] - amu1) + ta2 * (J[2] - amu2);
            const float quad1 = tb0 * (J[3] - bmu0) + tb1 * (J[4] - bmu1) + tb2 * (J[5] - bmu2);
            w0[band] += s * (1.0f + quad0);
            w1[band] += s * (1.0f + quad1);
        }
    }

    // ---- Phase 4: loss terms ----
    float d0 = 0.f, d1 = 0.f;
    #pragma unroll
    for (int q = 0; q < 25; ++q) { d0 += w0[q]; d1 += w1[q]; }

    float loss = 0.f;
    #pragma unroll
    for (int q = 0; q < 25; ++q) {
        if (q == 12) continue;                 // CENTER handled below
        const float dd = w1[q] - w0[q];        // off-diag: L = -W, sign cancels in square
        loss += dd * dd;
    }
    {   // CENTER band: L[i,CENTER] = d_i - W[i,i]
        const float dd = (d1 - w1[12]) - (d0 - w0[12]);
        loss += dd * dd;
    }

    // ---- Phase 5: block reduce + atomic ----
    #pragma unroll
    for (int off = 32; off >= 1; off >>= 1)
        loss += __shfl_down(loss, off, 64);
    if ((tid & 63) == 0) s_red[tid >> 6] = loss;
    __syncthreads();
    if (tid == 0) {
        const float total = s_red[0] + s_red[1] + s_red[2] + s_red[3];
        atomicAdd(out, total * inv_denom);
    }
}

} // namespace

extern "C" void kernel_launch(void* const* d_in, const int* in_sizes, int n_in,
                              void* d_out, int out_size, void* d_ws, size_t ws_size,
                              hipStream_t stream) {
    const float* content  = (const float*)d_in[0];
    const float* stylized = (const float*)d_in[1];
    float* out = (float*)d_out;

    const int B = in_sizes[0] / (3 * H * Wd);
    const float inv_denom =
        1.0f / ((float)B * (float)(H * Wd) * (float)(H * Wd));

    // d_out is poisoned once and never re-poisoned between replays: zero it ourselves.
    hipMemsetAsync(out, 0, (size_t)out_size * sizeof(float), stream);

    dim3 grid(Wd / TILE, H / TILE, B);
    matting_loss_kernel<<<grid, 256, 0, stream>>>(content, stylized, out, inv_denom);
}

// Round 2
// 31.165 us; speedup vs baseline: 1.2003x; 1.2003x over previous
//
#include <hip/hip_runtime.h>

namespace {

constexpr int H = 256;
constexpr int Wd = 256;
constexpr int TILE = 16;
constexpr float EPS9 = 1e-7f / 9.0f;
constexpr float NINTH = 1.0f / 9.0f;
// s_img row pitch in floats: 20 px * 8 ch + 4 pad -> rows shift banks by 4,
// keeping 16B alignment for float4 while breaking the 4-row bank collision.
constexpr int IPITCH = 164;

// One block = one 16x16 pixel tile of one batch image pair.
// LDS budget: s_img 20*164*4 = 13120 B, s_muk 10368 B, s_A 15552 B -> ~38.3 KB
// => 4 blocks/CU (whole 1024-block grid resident, no tail).
__global__ __launch_bounds__(256, 4)
void matting_loss_kernel(const float* __restrict__ content,
                         const float* __restrict__ stylized,
                         float* __restrict__ out,
                         float inv_denom)
{
    const int b  = blockIdx.z;
    const int x0 = blockIdx.x * TILE;
    const int y0 = blockIdx.y * TILE;
    const int tid = threadIdx.x;
    const int tx = tid & (TILE - 1);
    const int ty = tid >> 4;

    __shared__ __align__(16) float s_img[20 * IPITCH];     // [y][x*8 + m*4 + c], c<3 used
    __shared__ __align__(16) float s_muk[2][18][18][4];    // mu0,mu1,mu2, scale(=1/9 or 0)
    __shared__ __align__(16) float s_A[2][18][18][6];      // a00,a01,a02,a11,a12,a22
    __shared__ float s_red[4];

    const size_t bofs = (size_t)b * 3 * H * Wd;
    const float* img0 = content + bofs;
    const float* img1 = stylized + bofs;

    // ---- Phase 1: stage image tile + 2-halo (clamped; clamped pixels only ever
    //      multiply against zeroed center records, so finiteness suffices) ----
    for (int p = tid; p < 400; p += 256) {
        const int py = p / 20, px = p - py * 20;
        const int gy = min(max(y0 - 2 + py, 0), H - 1);
        const int gx = min(max(x0 - 2 + px, 0), Wd - 1);
        const int gi = gy * Wd + gx;
        float4 v0, v1;
        v0.x = img0[gi]; v0.y = img0[H * Wd + gi]; v0.z = img0[2 * H * Wd + gi]; v0.w = 0.f;
        v1.x = img1[gi]; v1.y = img1[H * Wd + gi]; v1.z = img1[2 * H * Wd + gi]; v1.w = 0.f;
        float* dst = &s_img[py * IPITCH + px * 8];
        *reinterpret_cast<float4*>(dst)     = v0;
        *reinterpret_cast<float4*>(dst + 4) = v1;
    }
    __syncthreads();

    // ---- Phase 2: per-window-center stats (mean + inverse covariance) ----
    for (int p = tid; p < 324; p += 256) {
        const int cy = p / 18, cx = p - cy * 18;
        const int gy = y0 - 1 + cy, gx = x0 - 1 + cx;
        const bool valid = (gy >= 1) && (gy <= H - 2) && (gx >= 1) && (gx <= Wd - 2);
        const float scale = valid ? NINTH : 0.0f;
        #pragma unroll
        for (int m = 0; m < 2; ++m) {
            float s0=0.f,s1=0.f,s2=0.f,q00=0.f,q01=0.f,q02=0.f,q11=0.f,q12=0.f,q22=0.f;
            #pragma unroll
            for (int wy = 0; wy < 3; ++wy)
                #pragma unroll
                for (int wx = 0; wx < 3; ++wx) {
                    const float4 v = *reinterpret_cast<const float4*>(
                        &s_img[(cy + wy) * IPITCH + (cx + wx) * 8 + m * 4]);
                    s0 += v.x; s1 += v.y; s2 += v.z;
                    q00 += v.x * v.x; q01 += v.x * v.y; q02 += v.x * v.z;
                    q11 += v.y * v.y; q12 += v.y * v.z; q22 += v.z * v.z;
                }
            const float mu0 = s0 * NINTH, mu1 = s1 * NINTH, mu2 = s2 * NINTH;
            const float c00 = q00 * NINTH - mu0 * mu0 + EPS9;
            const float c01 = q01 * NINTH - mu0 * mu1;
            const float c02 = q02 * NINTH - mu0 * mu2;
            const float c11 = q11 * NINTH - mu1 * mu1 + EPS9;
            const float c12 = q12 * NINTH - mu1 * mu2;
            const float c22 = q22 * NINTH - mu2 * mu2 + EPS9;
            const float m00 = c11 * c22 - c12 * c12;
            const float m01 = c02 * c12 - c01 * c22;
            const float m02 = c01 * c12 - c02 * c11;
            const float det = c00 * m00 + c01 * m01 + c02 * m02;
            // invalid centers never divide (det~0 possible on clamped data);
            // A = 0 + scale = 0 kills their contribution while staying finite.
            const float invdet = valid ? (1.0f / det) : 0.0f;
            float4 muk; muk.x = mu0; muk.y = mu1; muk.z = mu2; muk.w = scale;
            *reinterpret_cast<float4*>(&s_muk[m][cy][cx][0]) = muk;
            float* A = &s_A[m][cy][cx][0];
            float2 a0; a0.x = m00 * invdet;                  a0.y = m01 * invdet;
            float2 a1; a1.x = m02 * invdet;                  a1.y = (c00*c22 - c02*c02) * invdet;
            float2 a2; a2.x = (c01*c02 - c00*c12) * invdet;  a2.y = (c00*c11 - c01*c01) * invdet;
            reinterpret_cast<float2*>(A)[0] = a0;
            reinterpret_cast<float2*>(A)[1] = a1;
            reinterpret_cast<float2*>(A)[2] = a2;
        }
    }
    __syncthreads();

    // ---- Phase 3: per-pixel band accumulation via K/T hoist ----
    // w[band] = sum_c s*(1 + t_c.(J_band - mu_c))
    //         = [sum_c s*(1 - t_c.mu_c)] + [sum_c s*t_c] . J_band
    // with t_c = A_c (I_i - mu_c). Centers c in S(band): e=c-i, f=J-c in [-1,1].
    float w[25];
    float d0 = 0.f, d1 = 0.f, w1_12 = 0.f, loss = 0.f;

    #pragma unroll
    for (int m = 0; m < 2; ++m) {
        // per-center records for this pixel & image: k, s*t
        float ck[3][3];
        float cst[3][3][3];
        const float4 Ii = *reinterpret_cast<const float4*>(
            &s_img[(ty + 2) * IPITCH + (tx + 2) * 8 + m * 4]);
        #pragma unroll
        for (int ey = 0; ey < 3; ++ey)
        #pragma unroll
        for (int ex = 0; ex < 3; ++ex) {
            const float4 muk = *reinterpret_cast<const float4*>(&s_muk[m][ty + ey][tx + ex][0]);
            const float* A = &s_A[m][ty + ey][tx + ex][0];
            const float2 a0 = reinterpret_cast<const float2*>(A)[0];  // a00,a01
            const float2 a1 = reinterpret_cast<const float2*>(A)[1];  // a02,a11
            const float2 a2 = reinterpret_cast<const float2*>(A)[2];  // a12,a22
            const float u0 = Ii.x - muk.x, u1 = Ii.y - muk.y, u2 = Ii.z - muk.z;
            const float t0 = a0.x * u0 + a0.y * u1 + a1.x * u2;
            const float t1 = a0.y * u0 + a1.y * u1 + a2.x * u2;
            const float t2 = a1.x * u0 + a2.x * u1 + a2.y * u2;
            const float s = muk.w;
            cst[ey][ex][0] = s * t0;
            cst[ey][ex][1] = s * t1;
            cst[ey][ex][2] = s * t2;
            ck[ey][ex] = s * (1.0f - (t0 * muk.x + t1 * muk.y + t2 * muk.z));
        }

        #pragma unroll
        for (int by = 0; by < 5; ++by) {
            // row-partial sums over center rows ey in S(by) = [by-2, by] ∩ [0,2]
            float R[3][4];
            #pragma unroll
            for (int ex = 0; ex < 3; ++ex) {
                float rk = 0.f, r0 = 0.f, r1 = 0.f, r2 = 0.f;
                #pragma unroll
                for (int ey = 0; ey < 3; ++ey) {
                    if (ey >= by - 2 && ey <= by) {   // compile-time after unroll
                        rk += ck[ey][ex];
                        r0 += cst[ey][ex][0];
                        r1 += cst[ey][ex][1];
                        r2 += cst[ey][ex][2];
                    }
                }
                R[ex][0] = rk; R[ex][1] = r0; R[ex][2] = r1; R[ex][3] = r2;
            }
            #pragma unroll
            for (int bx = 0; bx < 5; ++bx) {
                float Tk = 0.f, T0 = 0.f, T1 = 0.f, T2 = 0.f;
                #pragma unroll
                for (int ex = 0; ex < 3; ++ex) {
                    if (ex >= bx - 2 && ex <= bx) {
                        Tk += R[ex][0]; T0 += R[ex][1]; T1 += R[ex][2]; T2 += R[ex][3];
                    }
                }
                const int band = by * 5 + bx;
                const float4 J = *reinterpret_cast<const float4*>(
                    &s_img[(ty + by) * IPITCH + (tx + bx) * 8 + m * 4]);
                const float wv = Tk + T0 * J.x + T1 * J.y + T2 * J.z;
                if (m == 0) {
                    w[band] = wv;
                    d0 += wv;
                } else {
                    d1 += wv;
                    if (band == 12) {
                        w1_12 = wv;
                    } else {
                        const float dd = wv - w[band];
                        loss += dd * dd;
                    }
                }
            }
        }
    }
    {   // CENTER band: L[i,CENTER] = d_i - W[i,i]
        const float ddc = (d1 - w1_12) - (d0 - w[12]);
        loss += ddc * ddc;
    }

    // ---- Phase 4: block reduce + one atomic ----
    #pragma unroll
    for (int off = 32; off >= 1; off >>= 1)
        loss += __shfl_down(loss, off, 64);
    if ((tid & 63) == 0) s_red[tid >> 6] = loss;
    __syncthreads();
    if (tid == 0) {
        const float total = s_red[0] + s_red[1] + s_red[2] + s_red[3];
        atomicAdd(out, total * inv_denom);
    }
}

} // namespace

extern "C" void kernel_launch(void* const* d_in, const int* in_sizes, int n_in,
                              void* d_out, int out_size, void* d_ws, size_t ws_size,
                              hipStream_t stream) {
    const float* content  = (const float*)d_in[0];
    const float* stylized = (const float*)d_in[1];
    float* out = (float*)d_out;

    const int B = in_sizes[0] / (3 * H * Wd);
    const float inv_denom =
        1.0f / ((float)B * (float)(H * Wd) * (float)(H * Wd));

    // d_out is poisoned once and never re-poisoned between replays: zero it ourselves.
    hipMemsetAsync(out, 0, (size_t)out_size * sizeof(float), stream);

    dim3 grid(Wd / TILE, H / TILE, B);
    matting_loss_kernel<<<grid, 256, 0, stream>>>(content, stylized, out, inv_denom);
}

// Round 3
// 29.808 us; speedup vs baseline: 1.2549x; 1.0455x over previous
//
#include <hip/hip_runtime.h>

namespace {

constexpr int H = 256;
constexpr int Wd = 256;
constexpr int TILE = 16;
constexpr float EPS9 = 1e-7f / 9.0f;
constexpr float NINTH = 1.0f / 9.0f;
// s_img row pitch in floats: 20 px * 8 ch + 4 pad -> consecutive rows shift
// bank sets by 4 while keeping 16B alignment for float4 accesses.
constexpr int IPITCH = 164;

// One block = one 16x16 pixel tile of one batch image pair.
// Key algebra:
//   W[i,j] = sum_{valid centers c ~ i,j} (1/9)(1 + (I_i-mu_c)^T A_c (I_j-mu_c))
//   row-sum d_i = #valid centers (window mean identity) -> identical for both
//   images, so the Laplacian diagonal cancels in the difference; and W is
//   symmetric, so only the 13 bands with delta >= 0 are needed (weight 2 for
//   the 12 off-center ones).
__global__ __launch_bounds__(256, 3)
void matting_loss_kernel(const float* __restrict__ content,
                         const float* __restrict__ stylized,
                         float* __restrict__ out,
                         float inv_denom)
{
    const int b  = blockIdx.z;
    const int x0 = blockIdx.x * TILE;
    const int y0 = blockIdx.y * TILE;
    const int tid = threadIdx.x;
    const int tx = tid & (TILE - 1);
    const int ty = tid >> 4;

    __shared__ __align__(16) float s_img[20 * IPITCH];     // [y][x*8 + m*4 + c], c<3 used
    __shared__ __align__(16) float s_muk[2][18][18][4];    // mu0,mu1,mu2, scale(=1/9 or 0)
    __shared__ __align__(16) float s_A[2][18][18][6];      // a00,a01,a02,a11,a12,a22
    __shared__ float s_red[4];

    const size_t bofs = (size_t)b * 3 * H * Wd;
    const float* img0 = content + bofs;
    const float* img1 = stylized + bofs;

    // ---- Phase 1: stage image tile + 2-halo (clamped; clamped pixels only ever
    //      multiply against zeroed center records, so finiteness suffices) ----
    for (int p = tid; p < 400; p += 256) {
        const int py = p / 20, px = p - py * 20;
        const int gy = min(max(y0 - 2 + py, 0), H - 1);
        const int gx = min(max(x0 - 2 + px, 0), Wd - 1);
        const int gi = gy * Wd + gx;
        float4 v0, v1;
        v0.x = img0[gi]; v0.y = img0[H * Wd + gi]; v0.z = img0[2 * H * Wd + gi]; v0.w = 0.f;
        v1.x = img1[gi]; v1.y = img1[H * Wd + gi]; v1.z = img1[2 * H * Wd + gi]; v1.w = 0.f;
        float* dst = &s_img[py * IPITCH + px * 8];
        *reinterpret_cast<float4*>(dst)     = v0;
        *reinterpret_cast<float4*>(dst + 4) = v1;
    }
    __syncthreads();

    // ---- Phase 2: per-window-center stats (mean + inverse covariance) ----
    for (int p = tid; p < 324; p += 256) {
        const int cy = p / 18, cx = p - cy * 18;
        const int gy = y0 - 1 + cy, gx = x0 - 1 + cx;
        const bool valid = (gy >= 1) && (gy <= H - 2) && (gx >= 1) && (gx <= Wd - 2);
        const float scale = valid ? NINTH : 0.0f;
        #pragma unroll
        for (int m = 0; m < 2; ++m) {
            float s0=0.f,s1=0.f,s2=0.f,q00=0.f,q01=0.f,q02=0.f,q11=0.f,q12=0.f,q22=0.f;
            #pragma unroll
            for (int wy = 0; wy < 3; ++wy)
                #pragma unroll
                for (int wx = 0; wx < 3; ++wx) {
                    const float4 v = *reinterpret_cast<const float4*>(
                        &s_img[(cy + wy) * IPITCH + (cx + wx) * 8 + m * 4]);
                    s0 += v.x; s1 += v.y; s2 += v.z;
                    q00 += v.x * v.x; q01 += v.x * v.y; q02 += v.x * v.z;
                    q11 += v.y * v.y; q12 += v.y * v.z; q22 += v.z * v.z;
                }
            const float mu0 = s0 * NINTH, mu1 = s1 * NINTH, mu2 = s2 * NINTH;
            const float c00 = q00 * NINTH - mu0 * mu0 + EPS9;
            const float c01 = q01 * NINTH - mu0 * mu1;
            const float c02 = q02 * NINTH - mu0 * mu2;
            const float c11 = q11 * NINTH - mu1 * mu1 + EPS9;
            const float c12 = q12 * NINTH - mu1 * mu2;
            const float c22 = q22 * NINTH - mu2 * mu2 + EPS9;
            const float m00 = c11 * c22 - c12 * c12;
            const float m01 = c02 * c12 - c01 * c22;
            const float m02 = c01 * c12 - c02 * c11;
            const float det = c00 * m00 + c01 * m01 + c02 * m02;
            // invalid centers never divide (det~0 possible on clamped data);
            // A = 0 + scale = 0 kills their contribution while staying finite.
            const float invdet = valid ? (1.0f / det) : 0.0f;
            float4 muk; muk.x = mu0; muk.y = mu1; muk.z = mu2; muk.w = scale;
            *reinterpret_cast<float4*>(&s_muk[m][cy][cx][0]) = muk;
            float* A = &s_A[m][cy][cx][0];
            float2 a0; a0.x = m00 * invdet;                  a0.y = m01 * invdet;
            float2 a1; a1.x = m02 * invdet;                  a1.y = (c00*c22 - c02*c02) * invdet;
            float2 a2; a2.x = (c01*c02 - c00*c12) * invdet;  a2.y = (c00*c11 - c01*c01) * invdet;
            reinterpret_cast<float2*>(A)[0] = a0;
            reinterpret_cast<float2*>(A)[1] = a1;
            reinterpret_cast<float2*>(A)[2] = a2;
        }
    }
    __syncthreads();

    // ---- Phase 3: per-pixel band accumulation via K/T hoist ----
    // w_m[band] = K_m(band) + T_m(band) . J_m(band), with per-center records
    //   t = A (I_i - mu); st = s*t; k = s*(1 - t.mu)
    // and K/T prefix-summed over the centers serving each band.
    // dd(band) = w1 - w0 = Tkd + T1.J1 - T0.J0   (Tkd from k1-k0 records).
    float st0[3][3][3];   // image0: s*t per center
    float st1[3][3][3];   // image1
    float ckd[3][3];      // k1 - k0 per center

    const float4 Ii0 = *reinterpret_cast<const float4*>(
        &s_img[(ty + 2) * IPITCH + (tx + 2) * 8 + 0]);
    const float4 Ii1 = *reinterpret_cast<const float4*>(
        &s_img[(ty + 2) * IPITCH + (tx + 2) * 8 + 4]);

    #pragma unroll
    for (int ey = 0; ey < 3; ++ey)
    #pragma unroll
    for (int ex = 0; ex < 3; ++ex) {
        float kacc;
        #pragma unroll
        for (int m = 0; m < 2; ++m) {
            const float4 muk = *reinterpret_cast<const float4*>(&s_muk[m][ty + ey][tx + ex][0]);
            const float* A = &s_A[m][ty + ey][tx + ex][0];
            const float2 a0 = reinterpret_cast<const float2*>(A)[0];  // a00,a01
            const float2 a1 = reinterpret_cast<const float2*>(A)[1];  // a02,a11
            const float2 a2 = reinterpret_cast<const float2*>(A)[2];  // a12,a22
            const float4 Ii = (m == 0) ? Ii0 : Ii1;
            const float u0 = Ii.x - muk.x, u1 = Ii.y - muk.y, u2 = Ii.z - muk.z;
            const float t0 = a0.x * u0 + a0.y * u1 + a1.x * u2;
            const float t1 = a0.y * u0 + a1.y * u1 + a2.x * u2;
            const float t2 = a1.x * u0 + a2.x * u1 + a2.y * u2;
            const float s = muk.w;
            const float k = s * (1.0f - (t0 * muk.x + t1 * muk.y + t2 * muk.z));
            if (m == 0) {
                st0[ey][ex][0] = s * t0; st0[ey][ex][1] = s * t1; st0[ey][ex][2] = s * t2;
                kacc = k;
            } else {
                st1[ey][ex][0] = s * t0; st1[ey][ex][1] = s * t1; st1[ey][ex][2] = s * t2;
                ckd[ey][ex] = k - kacc;
            }
        }
    }

    float loss2 = 0.f;   // bands 13..24 (weight 2)
    float loss1 = 0.f;   // center band 12 (weight 1)

    #pragma unroll
    for (int by = 2; by <= 4; ++by) {
        // column partials over center rows ey in [by-2, 2]
        float Rk[3], R0[3][3], R1[3][3];
        #pragma unroll
        for (int ex = 0; ex < 3; ++ex) {
            float rk = 0.f, r00 = 0.f, r01 = 0.f, r02 = 0.f, r10 = 0.f, r11 = 0.f, r12 = 0.f;
            #pragma unroll
            for (int ey = 0; ey < 3; ++ey) {
                if (ey >= by - 2) {   // compile-time after unroll
                    rk  += ckd[ey][ex];
                    r00 += st0[ey][ex][0]; r01 += st0[ey][ex][1]; r02 += st0[ey][ex][2];
                    r10 += st1[ey][ex][0]; r11 += st1[ey][ex][1]; r12 += st1[ey][ex][2];
                }
            }
            Rk[ex] = rk;
            R0[ex][0] = r00; R0[ex][1] = r01; R0[ex][2] = r02;
            R1[ex][0] = r10; R1[ex][1] = r11; R1[ex][2] = r12;
        }
        #pragma unroll
        for (int bx = 0; bx < 5; ++bx) {
            if (by == 2 && bx < 2) continue;   // only bands >= 12
            float Tk = 0.f, T00 = 0.f, T01 = 0.f, T02 = 0.f, T10 = 0.f, T11 = 0.f, T12 = 0.f;
            #pragma unroll
            for (int ex = 0; ex < 3; ++ex) {
                if (ex >= bx - 2 && ex <= bx) {
                    Tk  += Rk[ex];
                    T00 += R0[ex][0]; T01 += R0[ex][1]; T02 += R0[ex][2];
                    T10 += R1[ex][0]; T11 += R1[ex][1]; T12 += R1[ex][2];
                }
            }
            const float* J = &s_img[(ty + by) * IPITCH + (tx + bx) * 8];
            const float4 J0 = *reinterpret_cast<const float4*>(J);
            const float4 J1 = *reinterpret_cast<const float4*>(J + 4);
            const float dd = Tk + (T10 * J1.x + T11 * J1.y + T12 * J1.z)
                                - (T00 * J0.x + T01 * J0.y + T02 * J0.z);
            if (by == 2 && bx == 2) loss1 += dd * dd;
            else                    loss2 += dd * dd;
        }
    }

    float loss = 2.0f * loss2 + loss1;

    // ---- Phase 4: block reduce + one atomic ----
    #pragma unroll
    for (int off = 32; off >= 1; off >>= 1)
        loss += __shfl_down(loss, off, 64);
    if ((tid & 63) == 0) s_red[tid >> 6] = loss;
    __syncthreads();
    if (tid == 0) {
        const float total = s_red[0] + s_red[1] + s_red[2] + s_red[3];
        atomicAdd(out, total * inv_denom);
    }
}

} // namespace

extern "C" void kernel_launch(void* const* d_in, const int* in_sizes, int n_in,
                              void* d_out, int out_size, void* d_ws, size_t ws_size,
                              hipStream_t stream) {
    const float* content  = (const float*)d_in[0];
    const float* stylized = (const float*)d_in[1];
    float* out = (float*)d_out;

    const int B = in_sizes[0] / (3 * H * Wd);
    const float inv_denom =
        1.0f / ((float)B * (float)(H * Wd) * (float)(H * Wd));

    // d_out is poisoned once and never re-poisoned between replays: zero it ourselves.
    hipMemsetAsync(out, 0, (size_t)out_size * sizeof(float), stream);

    dim3 grid(Wd / TILE, H / TILE, B);
    matting_loss_kernel<<<grid, 256, 0, stream>>>(content, stylized, out, inv_denom);
}

// Round 4
// 18.675 us; speedup vs baseline: 2.0030x; 1.5961x over previous
//
#include <hip/hip_runtime.h>

namespace {

constexpr int H = 256;
constexpr int Wd = 256;
constexpr int TILE = 16;
constexpr float EPS9 = 1e-7f / 9.0f;
constexpr float NINTH = 1.0f / 9.0f;
// s_img row pitch in floats: 20 px * 8 ch + 4 pad -> consecutive rows shift
// bank sets by 4 while keeping 16B alignment for float4 accesses.
constexpr int IPITCH = 164;

// One block = one 16x16 pixel tile of one batch image pair.
// Key algebra:
//   W[i,j] = sum_{valid centers c ~ i,j} (1/9)(1 + (I_i-mu_c)^T A_c (I_j-mu_c))
//   row-sum d_i = #valid centers (window-mean identity) -> identical for both
//   images, so the Laplacian diagonal cancels in the difference; and W is
//   symmetric, so only the 13 bands with delta >= 0 are needed (weight 2 for
//   the 12 off-center ones).
// Finish: NO global atomic (1024 same-address atomicAdds serialize at the
// coherence point) — each block stores its partial to ws[bid]; kernel 2 reduces.
__global__ __launch_bounds__(256, 3)
void matting_loss_kernel(const float* __restrict__ content,
                         const float* __restrict__ stylized,
                         float* __restrict__ ws)
{
    const int b  = blockIdx.z;
    const int x0 = blockIdx.x * TILE;
    const int y0 = blockIdx.y * TILE;
    const int tid = threadIdx.x;
    const int tx = tid & (TILE - 1);
    const int ty = tid >> 4;

    __shared__ __align__(16) float s_img[20 * IPITCH];     // [y][x*8 + m*4 + c], c<3 used
    __shared__ __align__(16) float s_muk[2][18][18][4];    // mu0,mu1,mu2, scale(=1/9 or 0)
    __shared__ __align__(16) float s_A[2][18][18][6];      // a00,a01,a02,a11,a12,a22
    __shared__ float s_red[4];

    const size_t bofs = (size_t)b * 3 * H * Wd;
    const float* img0 = content + bofs;
    const float* img1 = stylized + bofs;

    // ---- Phase 1: stage image tile + 2-halo (clamped; clamped pixels only ever
    //      multiply against zeroed center records, so finiteness suffices) ----
    for (int p = tid; p < 400; p += 256) {
        const int py = p / 20, px = p - py * 20;
        const int gy = min(max(y0 - 2 + py, 0), H - 1);
        const int gx = min(max(x0 - 2 + px, 0), Wd - 1);
        const int gi = gy * Wd + gx;
        float4 v0, v1;
        v0.x = img0[gi]; v0.y = img0[H * Wd + gi]; v0.z = img0[2 * H * Wd + gi]; v0.w = 0.f;
        v1.x = img1[gi]; v1.y = img1[H * Wd + gi]; v1.z = img1[2 * H * Wd + gi]; v1.w = 0.f;
        float* dst = &s_img[py * IPITCH + px * 8];
        *reinterpret_cast<float4*>(dst)     = v0;
        *reinterpret_cast<float4*>(dst + 4) = v1;
    }
    __syncthreads();

    // ---- Phase 2: per-window-center stats (mean + inverse covariance) ----
    for (int p = tid; p < 324; p += 256) {
        const int cy = p / 18, cx = p - cy * 18;
        const int gy = y0 - 1 + cy, gx = x0 - 1 + cx;
        const bool valid = (gy >= 1) && (gy <= H - 2) && (gx >= 1) && (gx <= Wd - 2);
        const float scale = valid ? NINTH : 0.0f;
        #pragma unroll
        for (int m = 0; m < 2; ++m) {
            float s0=0.f,s1=0.f,s2=0.f,q00=0.f,q01=0.f,q02=0.f,q11=0.f,q12=0.f,q22=0.f;
            #pragma unroll
            for (int wy = 0; wy < 3; ++wy)
                #pragma unroll
                for (int wx = 0; wx < 3; ++wx) {
                    const float4 v = *reinterpret_cast<const float4*>(
                        &s_img[(cy + wy) * IPITCH + (cx + wx) * 8 + m * 4]);
                    s0 += v.x; s1 += v.y; s2 += v.z;
                    q00 += v.x * v.x; q01 += v.x * v.y; q02 += v.x * v.z;
                    q11 += v.y * v.y; q12 += v.y * v.z; q22 += v.z * v.z;
                }
            const float mu0 = s0 * NINTH, mu1 = s1 * NINTH, mu2 = s2 * NINTH;
            const float c00 = q00 * NINTH - mu0 * mu0 + EPS9;
            const float c01 = q01 * NINTH - mu0 * mu1;
            const float c02 = q02 * NINTH - mu0 * mu2;
            const float c11 = q11 * NINTH - mu1 * mu1 + EPS9;
            const float c12 = q12 * NINTH - mu1 * mu2;
            const float c22 = q22 * NINTH - mu2 * mu2 + EPS9;
            const float m00 = c11 * c22 - c12 * c12;
            const float m01 = c02 * c12 - c01 * c22;
            const float m02 = c01 * c12 - c02 * c11;
            const float det = c00 * m00 + c01 * m01 + c02 * m02;
            // invalid centers never divide (det~0 possible on clamped data);
            // A = 0 + scale = 0 kills their contribution while staying finite.
            const float invdet = valid ? (1.0f / det) : 0.0f;
            float4 muk; muk.x = mu0; muk.y = mu1; muk.z = mu2; muk.w = scale;
            *reinterpret_cast<float4*>(&s_muk[m][cy][cx][0]) = muk;
            float* A = &s_A[m][cy][cx][0];
            float2 a0; a0.x = m00 * invdet;                  a0.y = m01 * invdet;
            float2 a1; a1.x = m02 * invdet;                  a1.y = (c00*c22 - c02*c02) * invdet;
            float2 a2; a2.x = (c01*c02 - c00*c12) * invdet;  a2.y = (c00*c11 - c01*c01) * invdet;
            reinterpret_cast<float2*>(A)[0] = a0;
            reinterpret_cast<float2*>(A)[1] = a1;
            reinterpret_cast<float2*>(A)[2] = a2;
        }
    }
    __syncthreads();

    // ---- Phase 3: per-pixel band accumulation via K/T hoist ----
    // dd(band) = w1 - w0 = Tkd + T1.J1 - T0.J0, records t = A (I_i - mu),
    // st = s*t, ckd = (k1 - k0) with k = s*(1 - t.mu).
    float st0[3][3][3];
    float st1[3][3][3];
    float ckd[3][3];

    const float4 Ii0 = *reinterpret_cast<const float4*>(
        &s_img[(ty + 2) * IPITCH + (tx + 2) * 8 + 0]);
    const float4 Ii1 = *reinterpret_cast<const float4*>(
        &s_img[(ty + 2) * IPITCH + (tx + 2) * 8 + 4]);

    #pragma unroll
    for (int ey = 0; ey < 3; ++ey)
    #pragma unroll
    for (int ex = 0; ex < 3; ++ex) {
        float kacc;
        #pragma unroll
        for (int m = 0; m < 2; ++m) {
            const float4 muk = *reinterpret_cast<const float4*>(&s_muk[m][ty + ey][tx + ex][0]);
            const float* A = &s_A[m][ty + ey][tx + ex][0];
            const float2 a0 = reinterpret_cast<const float2*>(A)[0];  // a00,a01
            const float2 a1 = reinterpret_cast<const float2*>(A)[1];  // a02,a11
            const float2 a2 = reinterpret_cast<const float2*>(A)[2];  // a12,a22
            const float4 Ii = (m == 0) ? Ii0 : Ii1;
            const float u0 = Ii.x - muk.x, u1 = Ii.y - muk.y, u2 = Ii.z - muk.z;
            const float t0 = a0.x * u0 + a0.y * u1 + a1.x * u2;
            const float t1 = a0.y * u0 + a1.y * u1 + a2.x * u2;
            const float t2 = a1.x * u0 + a2.x * u1 + a2.y * u2;
            const float s = muk.w;
            const float k = s * (1.0f - (t0 * muk.x + t1 * muk.y + t2 * muk.z));
            if (m == 0) {
                st0[ey][ex][0] = s * t0; st0[ey][ex][1] = s * t1; st0[ey][ex][2] = s * t2;
                kacc = k;
            } else {
                st1[ey][ex][0] = s * t0; st1[ey][ex][1] = s * t1; st1[ey][ex][2] = s * t2;
                ckd[ey][ex] = k - kacc;
            }
        }
    }

    float loss2 = 0.f;   // bands 13..24 (weight 2, symmetry)
    float loss1 = 0.f;   // center band 12 (weight 1)

    #pragma unroll
    for (int by = 2; by <= 4; ++by) {
        float Rk[3], R0[3][3], R1[3][3];
        #pragma unroll
        for (int ex = 0; ex < 3; ++ex) {
            float rk = 0.f, r00 = 0.f, r01 = 0.f, r02 = 0.f, r10 = 0.f, r11 = 0.f, r12 = 0.f;
            #pragma unroll
            for (int ey = 0; ey < 3; ++ey) {
                if (ey >= by - 2) {   // compile-time after unroll
                    rk  += ckd[ey][ex];
                    r00 += st0[ey][ex][0]; r01 += st0[ey][ex][1]; r02 += st0[ey][ex][2];
                    r10 += st1[ey][ex][0]; r11 += st1[ey][ex][1]; r12 += st1[ey][ex][2];
                }
            }
            Rk[ex] = rk;
            R0[ex][0] = r00; R0[ex][1] = r01; R0[ex][2] = r02;
            R1[ex][0] = r10; R1[ex][1] = r11; R1[ex][2] = r12;
        }
        #pragma unroll
        for (int bx = 0; bx < 5; ++bx) {
            if (by == 2 && bx < 2) continue;   // only bands >= 12
            float Tk = 0.f, T00 = 0.f, T01 = 0.f, T02 = 0.f, T10 = 0.f, T11 = 0.f, T12 = 0.f;
            #pragma unroll
            for (int ex = 0; ex < 3; ++ex) {
                if (ex >= bx - 2 && ex <= bx) {
                    Tk  += Rk[ex];
                    T00 += R0[ex][0]; T01 += R0[ex][1]; T02 += R0[ex][2];
                    T10 += R1[ex][0]; T11 += R1[ex][1]; T12 += R1[ex][2];
                }
            }
            const float* J = &s_img[(ty + by) * IPITCH + (tx + bx) * 8];
            const float4 J0 = *reinterpret_cast<const float4*>(J);
            const float4 J1 = *reinterpret_cast<const float4*>(J + 4);
            const float dd = Tk + (T10 * J1.x + T11 * J1.y + T12 * J1.z)
                                - (T00 * J0.x + T01 * J0.y + T02 * J0.z);
            if (by == 2 && bx == 2) loss1 += dd * dd;
            else                    loss2 += dd * dd;
        }
    }

    float loss = 2.0f * loss2 + loss1;

    // ---- Phase 4: block reduce, then ONE plain store per block ----
    #pragma unroll
    for (int off = 32; off >= 1; off >>= 1)
        loss += __shfl_down(loss, off, 64);
    if ((tid & 63) == 0) s_red[tid >> 6] = loss;
    __syncthreads();
    if (tid == 0) {
        const int bid = (blockIdx.z * gridDim.y + blockIdx.y) * gridDim.x + blockIdx.x;
        ws[bid] = s_red[0] + s_red[1] + s_red[2] + s_red[3];
    }
}

// Kernel 2: deterministic reduction of the per-block partials.
__global__ __launch_bounds__(256)
void reduce_kernel(const float* __restrict__ ws, float* __restrict__ out,
                   int n, float inv_denom)
{
    __shared__ float s_red[4];
    const int tid = threadIdx.x;
    float acc = 0.f;
    for (int i = tid; i < n; i += 256) acc += ws[i];
    #pragma unroll
    for (int off = 32; off >= 1; off >>= 1)
        acc += __shfl_down(acc, off, 64);
    if ((tid & 63) == 0) s_red[tid >> 6] = acc;
    __syncthreads();
    if (tid == 0)
        out[0] = (s_red[0] + s_red[1] + s_red[2] + s_red[3]) * inv_denom;
}

} // namespace

extern "C" void kernel_launch(void* const* d_in, const int* in_sizes, int n_in,
                              void* d_out, int out_size, void* d_ws, size_t ws_size,
                              hipStream_t stream) {
    const float* content  = (const float*)d_in[0];
    const float* stylized = (const float*)d_in[1];
    float* out = (float*)d_out;
    float* ws  = (float*)d_ws;

    const int B = in_sizes[0] / (3 * H * Wd);
    const float inv_denom =
        1.0f / ((float)B * (float)(H * Wd) * (float)(H * Wd));

    dim3 grid(Wd / TILE, H / TILE, B);
    const int nblocks = grid.x * grid.y * grid.z;
    matting_loss_kernel<<<grid, 256, 0, stream>>>(content, stylized, ws);
    reduce_kernel<<<1, 256, 0, stream>>>(ws, out, nblocks, inv_denom);
}